// Round 4
// baseline (235.896 us; speedup 1.0000x reference)
//
#include <hip/hip_runtime.h>

// Problem shape (from reference): B=32, C=256, H=W=64
#define BATCH 32
#define CHANS 256
#define HWSZ  4096                    // 64*64
#define NSLAB (BATCH * CHANS)         // 8192 blocks
#define INV_COUNT (1.0f / 131072.0f)  // 1 / (B*H*W)
#define HIST_N 10000

typedef float f4 __attribute__((ext_vector_type(4)));

// Tiny kernel, runs first: seed energy output with td_energy (atomic base)
// and produce hist output. 40 blocks — negligible.
__global__ __launch_bounds__(256) void init_small(
    const float* __restrict__ td_energy, const float* __restrict__ td_hist,
    float* __restrict__ out_energy, float* __restrict__ out_hist) {
    const int i = blockIdx.x * 256 + threadIdx.x;
    if (i < CHANS) out_energy[i] = td_energy[i];
    if (i < HIST_N) out_hist[i] = td_hist[i] + 1.0f;
}

// One block per (b, c) slab of 4096 contiguous floats.
// Fused: copy slab to output (NT stores) + abs-sum reduce + one scaled
// atomicAdd per block directly into out_energy.
__global__ __launch_bounds__(256) void fused_copy_reduce(
    const float* __restrict__ in, float* __restrict__ out,
    float* __restrict__ out_energy) {
    const int slab = blockIdx.x;            // = b*CHANS + c
    const int c = slab & (CHANS - 1);
    const size_t base = (size_t)slab * HWSZ;
    const f4* __restrict__ in4 = (const f4*)(in + base);
    f4* __restrict__ out4 = (f4*)(out + base);

    float s = 0.0f;
    // 4096 floats = 1024 f4; 256 threads x 4 iters, fully coalesced.
    #pragma unroll
    for (int i = 0; i < 4; ++i) {
        const int idx = threadIdx.x + i * 256;
        f4 v = in4[idx];
        __builtin_nontemporal_store(v, &out4[idx]);   // streaming store, skip LLC alloc
        s += fabsf(v.x) + fabsf(v.y) + fabsf(v.z) + fabsf(v.w);
    }

    // wave64 shuffle reduction
    #pragma unroll
    for (int off = 32; off > 0; off >>= 1) s += __shfl_down(s, off, 64);

    __shared__ float wsum[4];
    if ((threadIdx.x & 63) == 0) wsum[threadIdx.x >> 6] = s;
    __syncthreads();
    if (threadIdx.x == 0) {
        atomicAdd(&out_energy[c],
                  (wsum[0] + wsum[1] + wsum[2] + wsum[3]) * INV_COUNT);
    }
}

extern "C" void kernel_launch(void* const* d_in, const int* in_sizes, int n_in,
                              void* d_out, int out_size, void* d_ws, size_t ws_size,
                              hipStream_t stream) {
    const float* data_in   = (const float*)d_in[0];
    const float* td_energy = (const float*)d_in[1];
    const float* td_hist   = (const float*)d_in[2];

    float* out_data   = (float*)d_out;
    float* out_energy = out_data + (size_t)NSLAB * HWSZ;
    float* out_hist   = out_energy + CHANS;

    // Node 1: seed small outputs (energy base + hist). Same stream => ordered
    // before the atomics in node 2.
    init_small<<<(HIST_N + 255) / 256, 256, 0, stream>>>(
        td_energy, td_hist, out_energy, out_hist);

    // Node 2: the 268 MB streaming pass.
    fused_copy_reduce<<<NSLAB, 256, 0, stream>>>(data_in, out_data, out_energy);
}